// Round 2
// baseline (298.663 us; speedup 1.0000x reference)
//
#include <hip/hip_runtime.h>
#include <hip/hip_bf16.h>

#define NQ   50000
#define NKV  50000
#define CC   128
#define GG   8
#define SS   16
#define CSH  16

typedef short bf16x8 __attribute__((ext_vector_type(8)));
typedef float f32x4  __attribute__((ext_vector_type(4)));

__device__ __forceinline__ float bf_lo(unsigned u){ union{unsigned x; float f;} v; v.x = u << 16;        return v.f; }
__device__ __forceinline__ float bf_hi(unsigned u){ union{unsigned x; float f;} v; v.x = u & 0xffff0000u; return v.f; }
__device__ __forceinline__ short f2bfs(float f){
    __hip_bfloat16 h = __float2bfloat16(f);
    return *reinterpret_cast<short*>(&h);
}

// Load 16 contiguous bf16 (32B, 16B-aligned) -> 16 fp32
__device__ __forceinline__ void load16bf(const __hip_bfloat16* ptr, float* o){
    const uint4* p4 = reinterpret_cast<const uint4*>(ptr);
    uint4 a = p4[0]; uint4 b = p4[1];
    o[0]=bf_lo(a.x);  o[1]=bf_hi(a.x);  o[2]=bf_lo(a.y);  o[3]=bf_hi(a.y);
    o[4]=bf_lo(a.z);  o[5]=bf_hi(a.z);  o[6]=bf_lo(a.w);  o[7]=bf_hi(a.w);
    o[8]=bf_lo(b.x);  o[9]=bf_hi(b.x);  o[10]=bf_lo(b.y); o[11]=bf_hi(b.y);
    o[12]=bf_lo(b.z); o[13]=bf_hi(b.z); o[14]=bf_lo(b.w); o[15]=bf_hi(b.w);
}

// Load 8 contiguous f32, convert to bf16x8 fragment
__device__ __forceinline__ bf16x8 cvt8(const float* p){
    const float4* q = reinterpret_cast<const float4*>(p);
    float4 u = q[0], v = q[1];
    bf16x8 r;
    r[0]=f2bfs(u.x); r[1]=f2bfs(u.y); r[2]=f2bfs(u.z); r[3]=f2bfs(u.w);
    r[4]=f2bfs(v.x); r[5]=f2bfs(v.y); r[6]=f2bfs(v.z); r[7]=f2bfs(v.w);
    return r;
}

// ---------------------------------------------------------------------------
// Kernel 0: pack f32 weight matrices to bf16 in workspace.
// grid (16, 3), 256 threads. Biases stay f32 (added in f32 in the epilogue).
// ---------------------------------------------------------------------------
__global__ __launch_bounds__(256) void pack_weights(
    const float* __restrict__ Wq, const float* __restrict__ Wk,
    const float* __restrict__ Wv, __hip_bfloat16* __restrict__ Wb)
{
    const int which = blockIdx.y;
    const float* W = (which == 0) ? Wq : (which == 1) ? Wk : Wv;
    __hip_bfloat16* dW = Wb + (size_t)which * CC * CC;
    const int t = blockIdx.x * 256 + threadIdx.x;   // [0, 4096)
    #pragma unroll
    for (int i = t; i < CC * CC; i += 4096) {
        __hip_bfloat16 h; *reinterpret_cast<short*>(&h) = f2bfs(W[i]);
        dW[i] = h;
    }
}

// ---------------------------------------------------------------------------
// Kernel 1: Q/K/V projections.  out[n][c] = sum_k src[n][k] * W[c][k] + b[c]
// One wave computes a 16-row x 128-col strip via 8 col-tiles of
// mfma_f32_16x16x32_bf16 (K=128 -> 4 MFMA per tile). No LDS.
//   A-frag: lane holds A[m=lane&15][k = (lane>>4)*8 + j]   (f32->bf16 in-reg)
//   B-frag: lane holds B[k=(lane>>4)*8+j][n=lane&15] = W[c0+(lane&15)][k]
//   C/D   : col = lane&15, row = (lane>>4)*4 + reg
// blockIdx.y selects projection (0=Q from x, 1=K, 2=V from x2).
// ---------------------------------------------------------------------------
__global__ __launch_bounds__(256) void qkv_gemm(
    const float* __restrict__ x,
    const float* __restrict__ x2,
    const __hip_bfloat16* __restrict__ Wb,   // 3 x (128x128) bf16, packed
    const float* __restrict__ bq, const float* __restrict__ bk,
    const float* __restrict__ bv,
    __hip_bfloat16* __restrict__ Qf,
    __hip_bfloat16* __restrict__ Kf,
    __hip_bfloat16* __restrict__ Vf)
{
    const int which = blockIdx.y;
    const float* src;  const float* bias;  __hip_bfloat16* dst;
    int nrows;
    if (which == 0)      { src = x;  bias = bq; dst = Qf; nrows = NQ;  }
    else if (which == 1) { src = x2; bias = bk; dst = Kf; nrows = NKV; }
    else                 { src = x2; bias = bv; dst = Vf; nrows = NKV; }
    const __hip_bfloat16* W = Wb + (size_t)which * CC * CC;

    const int wave = threadIdx.x >> 6;
    const int lane = threadIdx.x & 63;
    const int m0   = (blockIdx.x * 4 + wave) * 16;
    if (m0 >= nrows) return;               // wave-uniform exit
    const int r  = lane & 15;
    const int kq = lane >> 4;

    const float* xrow = src + (size_t)(m0 + r) * CC + kq * 8;
    bf16x8 a0 = cvt8(xrow);
    bf16x8 a1 = cvt8(xrow + 32);
    bf16x8 a2 = cvt8(xrow + 64);
    bf16x8 a3 = cvt8(xrow + 96);

    #pragma unroll
    for (int t = 0; t < 8; ++t) {
        const int c0 = t * 16;
        const __hip_bfloat16* wrow = W + (size_t)(c0 + r) * CC + kq * 8;
        bf16x8 b0 = *reinterpret_cast<const bf16x8*>(wrow);
        bf16x8 b1 = *reinterpret_cast<const bf16x8*>(wrow + 32);
        bf16x8 b2 = *reinterpret_cast<const bf16x8*>(wrow + 64);
        bf16x8 b3 = *reinterpret_cast<const bf16x8*>(wrow + 96);
        f32x4 acc = {0.f, 0.f, 0.f, 0.f};
        acc = __builtin_amdgcn_mfma_f32_16x16x32_bf16(a0, b0, acc, 0, 0, 0);
        acc = __builtin_amdgcn_mfma_f32_16x16x32_bf16(a1, b1, acc, 0, 0, 0);
        acc = __builtin_amdgcn_mfma_f32_16x16x32_bf16(a2, b2, acc, 0, 0, 0);
        acc = __builtin_amdgcn_mfma_f32_16x16x32_bf16(a3, b3, acc, 0, 0, 0);

        const float bcol = bias[c0 + r];   // this lane's column bias (f32)
        #pragma unroll
        for (int i = 0; i < 4; ++i) {
            const int row = m0 + kq * 4 + i;
            *reinterpret_cast<short*>(
                reinterpret_cast<__hip_bfloat16*>(dst) + (size_t)row * CC + c0 + r)
                = f2bfs(acc[i] + bcol);
        }
    }
}

// ---------------------------------------------------------------------------
// Kernel 2: fused gather + positional MLP + grouped attention.
// One thread per (query n, group g). Per thread: 16 logits -> softmax -> PV.
// BN folded into W1/b1. Lanes g=0..7 of one n are adjacent -> K/V row reads
// coalesce into full 256B bursts.
// ---------------------------------------------------------------------------
__global__ __launch_bounds__(256) void attn_kernel(
    const float* __restrict__ p,        // (NQ,3)
    const float* __restrict__ p2,       // (NKV,3)
    const int*   __restrict__ idx,      // (NQ,SS)
    const float* __restrict__ W1,       // (3,3)
    const float* __restrict__ b1,       // (3,)
    const float* __restrict__ bn_gamma,
    const float* __restrict__ bn_beta,
    const float* __restrict__ bn_mean,
    const float* __restrict__ bn_var,
    const float* __restrict__ W2,       // (16,3)
    const float* __restrict__ b2,       // (16,)
    const __hip_bfloat16* __restrict__ Qf,  // (NQ,CC) bf16
    const __hip_bfloat16* __restrict__ Kf,  // (NKV,CC) bf16
    const __hip_bfloat16* __restrict__ Vf,  // (NKV,CC) bf16
    float* __restrict__ out)            // (NQ,CC) f32
{
    const int tid = blockIdx.x * 256 + threadIdx.x;
    if (tid >= NQ * GG) return;
    const int n = tid >> 3;
    const int g = tid & 7;

    // --- fold BN into the 3x3 conv ---
    float fw1[3][3], fb1[3];
    #pragma unroll
    for (int j = 0; j < 3; ++j) {
        const float sc = bn_gamma[j] * rsqrtf(bn_var[j] + 1e-5f);
        #pragma unroll
        for (int k = 0; k < 3; ++k) fw1[j][k] = W1[j*3 + k] * sc;
        fb1[j] = (b1[j] - bn_mean[j]) * sc + bn_beta[j];
    }
    const float w2q0 = W2[g*3+0],     w2q1 = W2[g*3+1],     w2q2 = W2[g*3+2];
    const float w2k0 = W2[(g+8)*3+0], w2k1 = W2[(g+8)*3+1], w2k2 = W2[(g+8)*3+2];
    const float b2q = b2[g], b2k = b2[g+8];

    const float px = p[(size_t)n*3+0];
    const float py = p[(size_t)n*3+1];
    const float pz = p[(size_t)n*3+2];

    // --- neighbor indices (16 ints = 64B aligned) ---
    int nbr[SS];
    {
        const int4* ip = reinterpret_cast<const int4*>(idx + (size_t)n * SS);
        int4 i0 = ip[0], i1 = ip[1], i2 = ip[2], i3 = ip[3];
        nbr[0]=i0.x; nbr[1]=i0.y; nbr[2]=i0.z; nbr[3]=i0.w;
        nbr[4]=i1.x; nbr[5]=i1.y; nbr[6]=i1.z; nbr[7]=i1.w;
        nbr[8]=i2.x; nbr[9]=i2.y; nbr[10]=i2.z; nbr[11]=i2.w;
        nbr[12]=i3.x; nbr[13]=i3.y; nbr[14]=i3.z; nbr[15]=i3.w;
    }

    // --- query fragment for this group ---
    float q[CSH];
    load16bf(Qf + (size_t)n * CC + g * CSH, q);

    // --- pass 1: logits ---
    float lg[SS];
    #pragma unroll
    for (int s = 0; s < SS; ++s) {
        const int i = nbr[s];
        const float rx = p2[(size_t)i*3+0] - px;
        const float ry = p2[(size_t)i*3+1] - py;
        const float rz = p2[(size_t)i*3+2] - pz;
        const float h0 = fmaxf(fw1[0][0]*rx + fw1[0][1]*ry + fw1[0][2]*rz + fb1[0], 0.f);
        const float h1 = fmaxf(fw1[1][0]*rx + fw1[1][1]*ry + fw1[1][2]*rz + fb1[1], 0.f);
        const float h2 = fmaxf(fw1[2][0]*rx + fw1[2][1]*ry + fw1[2][2]*rz + fb1[2], 0.f);
        const float prq = w2q0*h0 + w2q1*h1 + w2q2*h2 + b2q;
        const float prk = w2k0*h0 + w2k1*h1 + w2k2*h2 + b2k;
        float kk[CSH];
        load16bf(Kf + (size_t)i * CC + g * CSH, kk);
        float d = 0.f;
        #pragma unroll
        for (int c = 0; c < CSH; ++c) d += (kk[c] + prk) * (q[c] + prq);
        lg[s] = d * 0.25f;   // 1/sqrt(CS) = 0.25
    }

    // --- softmax over the 16 neighbors ---
    float mx = lg[0];
    #pragma unroll
    for (int s = 1; s < SS; ++s) mx = fmaxf(mx, lg[s]);
    float sum = 0.f;
    #pragma unroll
    for (int s = 0; s < SS; ++s) { lg[s] = __expf(lg[s] - mx); sum += lg[s]; }
    const float inv = 1.f / sum;

    // --- pass 2: weighted V accumulation ---
    float acc[CSH];
    #pragma unroll
    for (int c = 0; c < CSH; ++c) acc[c] = 0.f;
    #pragma unroll
    for (int s = 0; s < SS; ++s) {
        const int i = nbr[s];
        float vv[CSH];
        load16bf(Vf + (size_t)i * CC + g * CSH, vv);
        const float ws = lg[s];
        #pragma unroll
        for (int c = 0; c < CSH; ++c) acc[c] += ws * vv[c];
    }

    // --- store 16 f32 (64B, four dwordx4; wave covers 4KB contiguous) ---
    float4* op = reinterpret_cast<float4*>(out + (size_t)n * CC + g * CSH);
    op[0] = make_float4(acc[0]*inv,  acc[1]*inv,  acc[2]*inv,  acc[3]*inv);
    op[1] = make_float4(acc[4]*inv,  acc[5]*inv,  acc[6]*inv,  acc[7]*inv);
    op[2] = make_float4(acc[8]*inv,  acc[9]*inv,  acc[10]*inv, acc[11]*inv);
    op[3] = make_float4(acc[12]*inv, acc[13]*inv, acc[14]*inv, acc[15]*inv);
}

// ---------------------------------------------------------------------------
extern "C" void kernel_launch(void* const* d_in, const int* in_sizes, int n_in,
                              void* d_out, int out_size, void* d_ws, size_t ws_size,
                              hipStream_t stream) {
    const float* p   = (const float*)d_in[0];
    const float* x   = (const float*)d_in[1];
    const float* p2  = (const float*)d_in[2];
    const float* x2  = (const float*)d_in[3];
    const int*   idx = (const int*)d_in[4];
    const float* Wq  = (const float*)d_in[5];
    const float* bq  = (const float*)d_in[6];
    const float* Wk  = (const float*)d_in[7];
    const float* bk  = (const float*)d_in[8];
    const float* Wv  = (const float*)d_in[9];
    const float* bv  = (const float*)d_in[10];
    const float* W1  = (const float*)d_in[11];
    const float* b1  = (const float*)d_in[12];
    const float* bng = (const float*)d_in[13];
    const float* bnb = (const float*)d_in[14];
    const float* bnm = (const float*)d_in[15];
    const float* bnv = (const float*)d_in[16];
    const float* W2  = (const float*)d_in[17];
    const float* b2  = (const float*)d_in[18];
    float* out = (float*)d_out;

    // workspace: Qf | Kf | Vf (bf16, 38.4 MB) | Wb (3x128x128 bf16, 96 KB)
    __hip_bfloat16* Qf = (__hip_bfloat16*)d_ws;
    __hip_bfloat16* Kf = Qf + (size_t)NQ  * CC;
    __hip_bfloat16* Vf = Kf + (size_t)NKV * CC;
    __hip_bfloat16* Wb = Vf + (size_t)NKV * CC;

    pack_weights<<<dim3(16, 3), 256, 0, stream>>>(Wq, Wk, Wv, Wb);

    // 50000 rows / (4 waves * 16 rows) = 781.25 -> 782 blocks; y: Q,K,V
    qkv_gemm<<<dim3(782, 3), 256, 0, stream>>>(
        x, x2, Wb, bq, bk, bv, Qf, Kf, Vf);

    const int nthreads = NQ * GG;
    attn_kernel<<<(nthreads + 255) / 256, 256, 0, stream>>>(
        p, p2, idx, W1, b1, bng, bnb, bnm, bnv, W2, b2, Qf, Kf, Vf, out);
}

// Round 4
// 215.805 us; speedup vs baseline: 1.3839x; 1.3839x over previous
//
#include <hip/hip_runtime.h>
#include <hip/hip_bf16.h>

#define NQ   50000
#define NKV  50000
#define CC   128
#define GG   8
#define SS   16
#define CSH  16

typedef short bf16x8 __attribute__((ext_vector_type(8)));
typedef float f32x4  __attribute__((ext_vector_type(4)));

__device__ __forceinline__ float bf_lo(unsigned u){ union{unsigned x; float f;} v; v.x = u << 16;        return v.f; }
__device__ __forceinline__ float bf_hi(unsigned u){ union{unsigned x; float f;} v; v.x = u & 0xffff0000u; return v.f; }
__device__ __forceinline__ unsigned short f2bfu(float f){
    __hip_bfloat16 h = __float2bfloat16(f);
    return *reinterpret_cast<unsigned short*>(&h);
}
__device__ __forceinline__ short f2bfs(float f){
    __hip_bfloat16 h = __float2bfloat16(f);
    return *reinterpret_cast<short*>(&h);
}

// Load 16 contiguous bf16 (32B, >=16B aligned) -> 16 fp32
__device__ __forceinline__ void load16bf(const __hip_bfloat16* ptr, float* o){
    const uint4* p4 = reinterpret_cast<const uint4*>(ptr);
    uint4 a = p4[0]; uint4 b = p4[1];
    o[0]=bf_lo(a.x);  o[1]=bf_hi(a.x);  o[2]=bf_lo(a.y);  o[3]=bf_hi(a.y);
    o[4]=bf_lo(a.z);  o[5]=bf_hi(a.z);  o[6]=bf_lo(a.w);  o[7]=bf_hi(a.w);
    o[8]=bf_lo(b.x);  o[9]=bf_hi(b.x);  o[10]=bf_lo(b.y); o[11]=bf_hi(b.y);
    o[12]=bf_lo(b.z); o[13]=bf_hi(b.z); o[14]=bf_lo(b.w); o[15]=bf_hi(b.w);
}

// Load 8 contiguous f32 (32B aligned), convert to bf16x8 fragment
__device__ __forceinline__ bf16x8 cvt8(const float* p){
    const float4* q = reinterpret_cast<const float4*>(p);
    float4 u = q[0], v = q[1];
    bf16x8 r;
    r[0]=f2bfs(u.x); r[1]=f2bfs(u.y); r[2]=f2bfs(u.z); r[3]=f2bfs(u.w);
    r[4]=f2bfs(v.x); r[5]=f2bfs(v.y); r[6]=f2bfs(v.z); r[7]=f2bfs(v.w);
    return r;
}

// ---------------------------------------------------------------------------
// Kernel 1: Q/K/V projections.  out[n][c] = sum_k src[n][k] * W[c][k] + b[c]
// Block = 256 threads = 4 waves, 128 rows/block (32 rows/wave).
// W (f32) is converted + staged once per block into LDS in MFMA A-fragment
// order so the main-loop ds_read_b128 is lane-contiguous (conflict-free).
// Operands: A = W-fragment (m-dim = channel), B = x-rows (n-dim = point row).
// C/D: col(lane&15) = x-row, row(kq*4+reg) = channel -> each lane owns 4
// consecutive channels of one output row -> packed 8B stores.
// blockIdx.y selects projection (0=Q from x, 1=K, 2=V from x2).
// ---------------------------------------------------------------------------
__global__ __launch_bounds__(256) void qkv_gemm(
    const float* __restrict__ x,
    const float* __restrict__ x2,
    const float* __restrict__ Wq, const float* __restrict__ Wk,
    const float* __restrict__ Wv,
    const float* __restrict__ bq, const float* __restrict__ bk,
    const float* __restrict__ bv,
    __hip_bfloat16* __restrict__ Qf,
    __hip_bfloat16* __restrict__ Kf,
    __hip_bfloat16* __restrict__ Vf)
{
    __shared__ short lds16[16384];   // 32 KB: 8 tiles x 4 kb x 64 lanes x 8 halfwords

    const int which = blockIdx.y;
    const float* src;  const float* W;  const float* bias;
    __hip_bfloat16* dst;
    if (which == 0)      { src = x;  W = Wq; bias = bq; dst = Qf; }
    else if (which == 1) { src = x2; W = Wk; bias = bk; dst = Kf; }
    else                 { src = x2; W = Wv; bias = bv; dst = Vf; }
    const int nrows = NQ;            // == NKV

    // --- stage W into LDS (f32 -> bf16), fragment order ---
    const int tid = threadIdx.x;
    #pragma unroll
    for (int i = 0; i < 8; ++i) {
        const int o   = tid * 64 + i * 8;          // linear f32 offset in W
        const bf16x8 v = cvt8(W + o);
        const int row = o >> 7, col = o & 127;
        const int lchunk = (((row >> 4) * 4 + (col >> 5)) << 6)
                         + (((col >> 3) & 3) << 4) + (row & 15);
        *reinterpret_cast<bf16x8*>(&lds16[lchunk * 8]) = v;
    }

    const int wave = tid >> 6;
    const int lane = tid & 63;
    const int r  = lane & 15;
    const int kq = lane >> 4;
    const int base = blockIdx.x * 128 + wave * 32;

    // --- B-fragments: this wave's 32 x-rows (2 m-tiles x 4 k-blocks) ---
    bf16x8 bfrag[2][4];
    #pragma unroll
    for (int mt = 0; mt < 2; ++mt) {
        int row = base + mt * 16 + r;
        if (row >= nrows) row = nrows - 1;         // clamp; stores guarded
        const float* xr = src + (size_t)row * CC + kq * 8;
        #pragma unroll
        for (int kb = 0; kb < 4; ++kb)
            bfrag[mt][kb] = cvt8(xr + kb * 32);
    }

    __syncthreads();

    // --- main loop over 8 column tiles ---
    #pragma unroll
    for (int t = 0; t < 8; ++t) {
        bf16x8 af[4];
        #pragma unroll
        for (int kb = 0; kb < 4; ++kb)
            af[kb] = *reinterpret_cast<const bf16x8*>(
                &lds16[(((t * 4 + kb) << 6) + lane) * 8]);

        f32x4 acc0 = {0.f,0.f,0.f,0.f}, acc1 = {0.f,0.f,0.f,0.f};
        #pragma unroll
        for (int kb = 0; kb < 4; ++kb) {
            acc0 = __builtin_amdgcn_mfma_f32_16x16x32_bf16(af[kb], bfrag[0][kb], acc0, 0, 0, 0);
            acc1 = __builtin_amdgcn_mfma_f32_16x16x32_bf16(af[kb], bfrag[1][kb], acc1, 0, 0, 0);
        }

        const float4 bi = *reinterpret_cast<const float4*>(bias + t * 16 + kq * 4);
        #pragma unroll
        for (int mt = 0; mt < 2; ++mt) {
            const int row = base + mt * 16 + r;
            if (row < nrows) {
                const f32x4 a = mt ? acc1 : acc0;
                uint2 pk;
                pk.x = (unsigned)f2bfu(a[0] + bi.x) | ((unsigned)f2bfu(a[1] + bi.y) << 16);
                pk.y = (unsigned)f2bfu(a[2] + bi.z) | ((unsigned)f2bfu(a[3] + bi.w) << 16);
                *reinterpret_cast<uint2*>(
                    reinterpret_cast<short*>(dst) + (size_t)row * CC + t * 16 + kq * 4) = pk;
            }
        }
    }
}

// ---------------------------------------------------------------------------
// Kernel 2: fused gather + positional MLP + grouped attention, SINGLE PASS
// with ONLINE (flash-style) softmax: running max m, rescale sum/acc by
// exp(m_old - m_new) on update. Numerically equal to shifted softmax —
// NO overflow even for logits in the hundreds (round-3 lesson: the
// positional-encoding term 16*prk*prq reaches ~250, exp() overflows
// without max subtraction). K and V gathered in the same s-iteration ->
// one latency epoch. BN folded into W1/b1.
// ---------------------------------------------------------------------------
__global__ __launch_bounds__(256) void attn_kernel(
    const float* __restrict__ p,        // (NQ,3)
    const float* __restrict__ p2,       // (NKV,3)
    const int*   __restrict__ idx,      // (NQ,SS)
    const float* __restrict__ W1,       // (3,3)
    const float* __restrict__ b1,       // (3,)
    const float* __restrict__ bn_gamma,
    const float* __restrict__ bn_beta,
    const float* __restrict__ bn_mean,
    const float* __restrict__ bn_var,
    const float* __restrict__ W2,       // (16,3)
    const float* __restrict__ b2,       // (16,)
    const __hip_bfloat16* __restrict__ Qf,  // (NQ,CC) bf16
    const __hip_bfloat16* __restrict__ Kf,  // (NKV,CC) bf16
    const __hip_bfloat16* __restrict__ Vf,  // (NKV,CC) bf16
    float* __restrict__ out)            // (NQ,CC) f32
{
    const int tid = blockIdx.x * 256 + threadIdx.x;
    if (tid >= NQ * GG) return;
    const int n = tid >> 3;
    const int g = tid & 7;

    // --- fold BN into the 3x3 conv ---
    float fw1[3][3], fb1[3];
    #pragma unroll
    for (int j = 0; j < 3; ++j) {
        const float sc = bn_gamma[j] * rsqrtf(bn_var[j] + 1e-5f);
        #pragma unroll
        for (int k = 0; k < 3; ++k) fw1[j][k] = W1[j*3 + k] * sc;
        fb1[j] = (b1[j] - bn_mean[j]) * sc + bn_beta[j];
    }
    const float w2q0 = W2[g*3+0],     w2q1 = W2[g*3+1],     w2q2 = W2[g*3+2];
    const float w2k0 = W2[(g+8)*3+0], w2k1 = W2[(g+8)*3+1], w2k2 = W2[(g+8)*3+2];
    const float b2q = b2[g], b2k = b2[g+8];

    const float px = p[(size_t)n*3+0];
    const float py = p[(size_t)n*3+1];
    const float pz = p[(size_t)n*3+2];

    // --- neighbor indices (16 ints = 64B aligned) ---
    int nbr[SS];
    {
        const int4* ip = reinterpret_cast<const int4*>(idx + (size_t)n * SS);
        int4 i0 = ip[0], i1 = ip[1], i2 = ip[2], i3 = ip[3];
        nbr[0]=i0.x; nbr[1]=i0.y; nbr[2]=i0.z; nbr[3]=i0.w;
        nbr[4]=i1.x; nbr[5]=i1.y; nbr[6]=i1.z; nbr[7]=i1.w;
        nbr[8]=i2.x; nbr[9]=i2.y; nbr[10]=i2.z; nbr[11]=i2.w;
        nbr[12]=i3.x; nbr[13]=i3.y; nbr[14]=i3.z; nbr[15]=i3.w;
    }

    // --- query fragment for this group ---
    float q[CSH];
    load16bf(Qf + (size_t)n * CC + g * CSH, q);

    // --- single fused pass with online softmax ---
    float acc[CSH];
    #pragma unroll
    for (int c = 0; c < CSH; ++c) acc[c] = 0.f;
    float sum = 0.f;
    float m = -3.0e38f;

    #pragma unroll 4
    for (int s = 0; s < SS; ++s) {
        const int i = nbr[s];
        const size_t eoff = (size_t)i * CC + g * CSH;

        float kk[CSH], vv[CSH];
        load16bf(Kf + eoff, kk);
        load16bf(Vf + eoff, vv);

        const float rx = p2[(size_t)i*3+0] - px;
        const float ry = p2[(size_t)i*3+1] - py;
        const float rz = p2[(size_t)i*3+2] - pz;
        const float h0 = fmaxf(fw1[0][0]*rx + fw1[0][1]*ry + fw1[0][2]*rz + fb1[0], 0.f);
        const float h1 = fmaxf(fw1[1][0]*rx + fw1[1][1]*ry + fw1[1][2]*rz + fb1[1], 0.f);
        const float h2 = fmaxf(fw1[2][0]*rx + fw1[2][1]*ry + fw1[2][2]*rz + fb1[2], 0.f);
        const float prq = w2q0*h0 + w2q1*h1 + w2q2*h2 + b2q;
        const float prk = w2k0*h0 + w2k1*h1 + w2k2*h2 + b2k;

        float d = 0.f;
        #pragma unroll
        for (int c = 0; c < CSH; ++c) d += (kk[c] + prk) * (q[c] + prq);
        d *= 0.25f;   // 1/sqrt(CS) = 0.25

        const float mnew = fmaxf(m, d);
        const float corr = __expf(m - mnew);   // 1.0 when max unchanged
        const float w    = __expf(d - mnew);
        sum = sum * corr + w;
        #pragma unroll
        for (int c = 0; c < CSH; ++c) acc[c] = acc[c] * corr + w * vv[c];
        m = mnew;
    }

    const float inv = 1.f / sum;

    // --- store 16 f32 (64B; 8 lanes of one n cover 512B contiguous) ---
    float4* op = reinterpret_cast<float4*>(out + (size_t)n * CC + g * CSH);
    op[0] = make_float4(acc[0]*inv,  acc[1]*inv,  acc[2]*inv,  acc[3]*inv);
    op[1] = make_float4(acc[4]*inv,  acc[5]*inv,  acc[6]*inv,  acc[7]*inv);
    op[2] = make_float4(acc[8]*inv,  acc[9]*inv,  acc[10]*inv, acc[11]*inv);
    op[3] = make_float4(acc[12]*inv, acc[13]*inv, acc[14]*inv, acc[15]*inv);
}

// ---------------------------------------------------------------------------
extern "C" void kernel_launch(void* const* d_in, const int* in_sizes, int n_in,
                              void* d_out, int out_size, void* d_ws, size_t ws_size,
                              hipStream_t stream) {
    const float* p   = (const float*)d_in[0];
    const float* x   = (const float*)d_in[1];
    const float* p2  = (const float*)d_in[2];
    const float* x2  = (const float*)d_in[3];
    const int*   idx = (const int*)d_in[4];
    const float* Wq  = (const float*)d_in[5];
    const float* bq  = (const float*)d_in[6];
    const float* Wk  = (const float*)d_in[7];
    const float* bk  = (const float*)d_in[8];
    const float* Wv  = (const float*)d_in[9];
    const float* bv  = (const float*)d_in[10];
    const float* W1  = (const float*)d_in[11];
    const float* b1  = (const float*)d_in[12];
    const float* bng = (const float*)d_in[13];
    const float* bnb = (const float*)d_in[14];
    const float* bnm = (const float*)d_in[15];
    const float* bnv = (const float*)d_in[16];
    const float* W2  = (const float*)d_in[17];
    const float* b2  = (const float*)d_in[18];
    float* out = (float*)d_out;

    // workspace: Qf | Kf | Vf (bf16, 38.4 MB)
    __hip_bfloat16* Qf = (__hip_bfloat16*)d_ws;
    __hip_bfloat16* Kf = Qf + (size_t)NQ  * CC;
    __hip_bfloat16* Vf = Kf + (size_t)NKV * CC;

    // 50000 rows / 128 rows-per-block = 390.6 -> 391 blocks; y: Q,K,V
    qkv_gemm<<<dim3(391, 3), 256, 0, stream>>>(
        x, x2, Wq, Wk, Wv, bq, bk, bv, Qf, Kf, Vf);

    const int nthreads = NQ * GG;
    attn_kernel<<<(nthreads + 255) / 256, 256, 0, stream>>>(
        p, p2, idx, W1, b1, bng, bnb, bnm, bnv, W2, b2, Qf, Kf, Vf, out);
}